// Round 1
// baseline (2054.240 us; speedup 1.0000x reference)
//
#include <hip/hip_runtime.h>

typedef __attribute__((ext_vector_type(8))) short short8;
typedef __attribute__((ext_vector_type(4))) float f32x4;

__device__ __forceinline__ ushort f2bf(float x) {
  unsigned u = __builtin_bit_cast(unsigned, x);
  u = (u + 0x7fffu + ((u >> 16) & 1u)) >> 16;
  return (ushort)u;
}
__device__ __forceinline__ float bf2f(ushort x) {
  return __builtin_bit_cast(float, ((unsigned)x) << 16);
}

// ---------------- input fp32 -> bf16 ----------------
__global__ __launch_bounds__(256) void k_cvt(const float* __restrict__ in,
                                             ushort* __restrict__ out, int n4) {
  int i = blockIdx.x * 256 + threadIdx.x;
  if (i >= n4) return;
  float4 v = reinterpret_cast<const float4*>(in)[i];
  ushort4 o;
  o.x = f2bf(v.x); o.y = f2bf(v.y); o.z = f2bf(v.z); o.w = f2bf(v.w);
  reinterpret_cast<ushort4*>(out)[i] = o;
}

// ------------- transpose fp32 [K][N] -> bf16 [N][K] -------------
__global__ __launch_bounds__(256) void k_transpose(const float* __restrict__ W,
                                                   ushort* __restrict__ Wt,
                                                   int N, int K) {
  __shared__ float tile[32][33];
  int bx = blockIdx.x * 32;  // N dim
  int by = blockIdx.y * 32;  // K dim
  int tx = threadIdx.x, ty = threadIdx.y;  // 32 x 8
#pragma unroll
  for (int i = 0; i < 32; i += 8)
    tile[ty + i][tx] = W[(size_t)(by + ty + i) * N + bx + tx];
  __syncthreads();
#pragma unroll
  for (int i = 0; i < 32; i += 8)
    Wt[(size_t)(bx + ty + i) * K + by + tx] = f2bf(tile[tx][ty + i]);
}

// ------------- GEMM: C[M][N] fp32 = A[M][K] bf16 * Bt[N][K] bf16 -------------
// 128x128 tile, BK=32, 256 threads (4 waves, 2x2 of 64x64), mfma 16x16x32 bf16
__global__ __launch_bounds__(256) void k_gemm(const ushort* __restrict__ A,
                                              const ushort* __restrict__ Bt,
                                              float* __restrict__ C,
                                              int K, int N) {
  __shared__ ushort lsA[128][40];
  __shared__ ushort lsB[128][40];
  const int tid = threadIdx.x;
  const int bm = blockIdx.x, bn = blockIdx.y;
  const int w = tid >> 6, l = tid & 63;
  const int wm = (w >> 1) * 64, wn = (w & 1) * 64;
  const int lr = l & 15, lg = l >> 4;
  f32x4 acc[4][4] = {};
  const int sr = tid >> 2;          // 0..63
  const int sk = (tid & 3) * 8;     // 0,8,16,24
  const ushort* Ag = A + (size_t)bm * 128 * K + (size_t)sr * K + sk;
  const ushort* Bg = Bt + (size_t)bn * 128 * K + (size_t)sr * K + sk;
  uint4 a0 = *(const uint4*)(Ag);
  uint4 a1 = *(const uint4*)(Ag + (size_t)64 * K);
  uint4 b0 = *(const uint4*)(Bg);
  uint4 b1 = *(const uint4*)(Bg + (size_t)64 * K);
  for (int kt = 0; kt < K; kt += 32) {
    __syncthreads();
    *(uint4*)&lsA[sr][sk] = a0;
    *(uint4*)&lsA[sr + 64][sk] = a1;
    *(uint4*)&lsB[sr][sk] = b0;
    *(uint4*)&lsB[sr + 64][sk] = b1;
    __syncthreads();
    if (kt + 32 < K) {
      a0 = *(const uint4*)(Ag + kt + 32);
      a1 = *(const uint4*)(Ag + (size_t)64 * K + kt + 32);
      b0 = *(const uint4*)(Bg + kt + 32);
      b1 = *(const uint4*)(Bg + (size_t)64 * K + kt + 32);
    }
    short8 af[4], bfr[4];
#pragma unroll
    for (int i = 0; i < 4; ++i)
      af[i] = *(const short8*)&lsA[wm + i * 16 + lr][lg * 8];
#pragma unroll
    for (int j = 0; j < 4; ++j)
      bfr[j] = *(const short8*)&lsB[wn + j * 16 + lr][lg * 8];
#pragma unroll
    for (int i = 0; i < 4; ++i)
#pragma unroll
      for (int j = 0; j < 4; ++j)
        acc[i][j] = __builtin_amdgcn_mfma_f32_16x16x32_bf16(af[i], bfr[j], acc[i][j], 0, 0, 0);
  }
  float* Cb = C + (size_t)(bm * 128 + wm + lg * 4) * N + bn * 128 + wn + lr;
#pragma unroll
  for (int i = 0; i < 4; ++i)
#pragma unroll
    for (int j = 0; j < 4; ++j)
#pragma unroll
      for (int r = 0; r < 4; ++r)
        Cb[(size_t)(i * 16 + r) * N + j * 16] = acc[i][j][r];
}

// ------------- SRU recurrence -------------
// U: [B*L][2*512*KK] fp32; Xres (KK==3): [B*L][1024] bf16; H out: [B*L][1024] bf16
template <int KK>
__global__ __launch_bounds__(64) void sru_rec(const float* __restrict__ U,
                                              const ushort* __restrict__ Xres,
                                              const float* __restrict__ v,
                                              const float* __restrict__ bb,
                                              ushort* __restrict__ H) {
  int tid = blockIdx.x * 64 + threadIdx.x;
  int b = tid >> 10, rem = tid & 1023, dir = rem >> 9, h = rem & 511;
  float vf = v[dir * 512 + h], vr = v[1024 + dir * 512 + h];
  float bfv = bb[dir * 512 + h], brv = bb[1024 + dir * 512 + h];
  const int rs = 1024 * KK;
  const float* Ub = U + (size_t)b * 512 * rs + dir * 512 * KK + h * KK;
  const ushort* Xb = Xres + (size_t)b * 512 * 1024 + dir * 512 + h;
  ushort* Hb = H + (size_t)b * 512 * 1024 + dir * 512 + h;
  const int tstep = dir ? -1 : 1;
  const int t0 = dir ? 511 : 0;

  float4 buf[4];
#pragma unroll
  for (int s = 0; s < 4; ++s) {
    int t = t0 + tstep * s;
    const float* up = Ub + (size_t)t * rs;
    buf[s].x = up[0]; buf[s].y = up[1]; buf[s].z = up[2];
    buf[s].w = (KK == 4) ? up[3] : bf2f(Xb[(size_t)t * 1024]);
  }
  float c = 0.f;
  for (int blk = 0; blk < 512; blk += 4) {
#pragma unroll
    for (int s = 0; s < 4; ++s) {
      const int step = blk + s;
      float4 cu = buf[s];
      if (step + 4 < 512) {
        int tn = t0 + tstep * (step + 4);
        const float* up = Ub + (size_t)tn * rs;
        buf[s].x = up[0]; buf[s].y = up[1]; buf[s].z = up[2];
        buf[s].w = (KK == 4) ? up[3] : bf2f(Xb[(size_t)tn * 1024]);
      }
      float f = 1.f / (1.f + __expf(-(cu.y + vf * c + bfv)));
      c = f * c + (1.f - f) * cu.x;
      float r = 1.f / (1.f + __expf(-(cu.z + vr * c + brv)));
      float hh = r * c + (1.f - r) * cu.w;
      int t = t0 + tstep * step;
      Hb[(size_t)t * 1024] = f2bf(hh);
    }
  }
}

// ------------- head: fc2s + log_softmax / tanh / softplus -------------
__global__ __launch_bounds__(256) void k_head(const float* __restrict__ Hcat,
                                              const float* __restrict__ b1l,
                                              const float* __restrict__ b1a,
                                              const float* __restrict__ w2l,
                                              const float* __restrict__ b2l,
                                              const float* __restrict__ w2m,
                                              const float* __restrict__ b2m,
                                              const float* __restrict__ w2k,
                                              const float* __restrict__ b2k,
                                              float* __restrict__ out) {
  __shared__ float hl[512], ha[512];
  __shared__ float part[25][8];
  __shared__ float vals[25];
  __shared__ float lse;
  const int row = blockIdx.x;
  const int tid = threadIdx.x;
  const float* Hr = Hcat + (size_t)row * 1024;
  for (int i = tid; i < 512; i += 256) {
    hl[i] = Hr[i] + b1l[i];
    ha[i] = Hr[512 + i] + b1a[i];
  }
  __syncthreads();
  const int o = tid >> 3, g = tid & 7;
  if (o < 25) {
    float s = 0.f;
    const int k0 = g * 64;
    if (o < 21) {
#pragma unroll 4
      for (int k = 0; k < 64; ++k) s += hl[k0 + k] * w2l[(size_t)(k0 + k) * 21 + o];
    } else if (o < 23) {
      for (int k = 0; k < 64; ++k) s += ha[k0 + k] * w2m[(k0 + k) * 2 + (o - 21)];
    } else {
      for (int k = 0; k < 64; ++k) s += ha[k0 + k] * w2k[(k0 + k) * 2 + (o - 23)];
    }
    part[o][g] = s;
  }
  __syncthreads();
  if (tid < 25) {
    float s = 0.f;
#pragma unroll
    for (int gg = 0; gg < 8; ++gg) s += part[tid][gg];
    s += (tid < 21) ? b2l[tid] : (tid < 23) ? b2m[tid - 21] : b2k[tid - 23];
    vals[tid] = s;
  }
  __syncthreads();
  if (tid == 0) {
    float m = vals[0];
    for (int j = 1; j < 21; ++j) m = fmaxf(m, vals[j]);
    float ss = 0.f;
    for (int j = 0; j < 21; ++j) ss += expf(vals[j] - m);
    lse = m + logf(ss);
  }
  __syncthreads();
  if (tid < 21) {
    out[(size_t)row * 21 + tid] = vals[tid] - lse;
  } else if (tid < 23) {
    out[172032 + row * 2 + (tid - 21)] = tanhf(vals[tid]) * 3.14159265358979323846f;
  } else if (tid < 25) {
    float x = vals[tid];
    float sp = (x > 20.f) ? x : log1pf(expf(x));
    out[188416 + row * 2 + (tid - 23)] = 5.f + sp;
  }
}

extern "C" void kernel_launch(void* const* d_in, const int* in_sizes, int n_in,
                              void* d_out, int out_size, void* d_ws, size_t ws_size,
                              hipStream_t stream) {
  (void)in_sizes; (void)n_in; (void)out_size; (void)ws_size;
  const float* input = (const float*)d_in[0];
  const float* sw[6]; const float* sv[6]; const float* sb[6];
  for (int l = 0; l < 6; ++l) {
    sw[l] = (const float*)d_in[2 + 3 * l];
    sv[l] = (const float*)d_in[3 + 3 * l];
    sb[l] = (const float*)d_in[4 + 3 * l];
  }
  const float* fc1lw = (const float*)d_in[20];
  const float* fc1lb = (const float*)d_in[21];
  const float* fc2lw = (const float*)d_in[22];
  const float* fc2lb = (const float*)d_in[23];
  const float* fc1aw = (const float*)d_in[24];
  const float* fc1ab = (const float*)d_in[25];
  const float* fc2mw = (const float*)d_in[26];
  const float* fc2mb = (const float*)d_in[27];
  const float* fc2kw = (const float*)d_in[28];
  const float* fc2kb = (const float*)d_in[29];

  char* ws = (char*)d_ws;
  float* U = (float*)ws;                                   // 128 MiB (also reused as Hcat)
  ushort* H0 = (ushort*)(ws + 134217728);                  // 16 MiB
  ushort* H1 = (ushort*)(ws + 150994944);                  // 16 MiB
  ushort* X0 = (ushort*)(ws + 167772160);                  // 8 MiB
  const size_t wbase = 176160768;
  ushort* Wtl[6];
  Wtl[0] = (ushort*)(ws + wbase);                          // 4 MiB
  for (int l = 1; l < 6; ++l)
    Wtl[l] = (ushort*)(ws + wbase + 4194304 + (size_t)(l - 1) * 6291456);  // 6 MiB each
  ushort* Wfc = (ushort*)(ws + wbase + 4194304 + 5ull * 6291456);          // 2 MiB
  float* Hcat = U;

  // 1. input -> bf16
  k_cvt<<<4096, 256, 0, stream>>>(input, X0, 8192 * 512 / 4);

  // 2. weight transposes -> bf16 [N][K]
  k_transpose<<<dim3(4096 / 32, 512 / 32), dim3(32, 8), 0, stream>>>(sw[0], Wtl[0], 4096, 512);
  for (int l = 1; l < 6; ++l)
    k_transpose<<<dim3(3072 / 32, 1024 / 32), dim3(32, 8), 0, stream>>>(sw[l], Wtl[l], 3072, 1024);
  k_transpose<<<dim3(512 / 32, 1024 / 32), dim3(32, 8), 0, stream>>>(fc1lw, Wfc, 512, 1024);
  k_transpose<<<dim3(512 / 32, 1024 / 32), dim3(32, 8), 0, stream>>>(fc1aw, Wfc + (size_t)512 * 1024, 512, 1024);

  // 3. SRU layers
  for (int l = 0; l < 6; ++l) {
    const ushort* Ain = (l == 0) ? X0 : ((l & 1) ? H0 : H1);
    ushort* Hout = (l & 1) ? H1 : H0;
    int K = (l == 0) ? 512 : 1024;
    int N = (l == 0) ? 4096 : 3072;
    k_gemm<<<dim3(64, N / 128), 256, 0, stream>>>(Ain, Wtl[l], U, K, N);
    if (l == 0)
      sru_rec<4><<<256, 64, 0, stream>>>(U, X0 /*unused*/, sv[l], sb[l], Hout);
    else
      sru_rec<3><<<256, 64, 0, stream>>>(U, Ain, sv[l], sb[l], Hout);
  }

  // 4. head fc1 (logits|angles fused): [8192,1024] = H5[8192,1024] x Wfc[1024,1024]
  k_gemm<<<dim3(64, 8), 256, 0, stream>>>(H1, Wfc, Hcat, 1024, 1024);

  // 5. head fc2 + activations
  k_head<<<8192, 256, 0, stream>>>(Hcat, fc1lb, fc1ab, fc2lw, fc2lb, fc2mw, fc2mb,
                                   fc2kw, fc2kb, (float*)d_out);
}

// Round 2
// 1898.958 us; speedup vs baseline: 1.0818x; 1.0818x over previous
//
#include <hip/hip_runtime.h>

typedef __attribute__((ext_vector_type(8))) short short8;
typedef __attribute__((ext_vector_type(4))) float f32x4;

__device__ __forceinline__ ushort f2bf(float x) {
  unsigned u = __builtin_bit_cast(unsigned, x);
  u = (u + 0x7fffu + ((u >> 16) & 1u)) >> 16;
  return (ushort)u;
}
__device__ __forceinline__ float bf2f(ushort x) {
  return __builtin_bit_cast(float, ((unsigned)x) << 16);
}

// ---------------- input fp32 -> bf16 ----------------
__global__ __launch_bounds__(256) void k_cvt(const float* __restrict__ in,
                                             ushort* __restrict__ out, int n4) {
  int i = blockIdx.x * 256 + threadIdx.x;
  if (i >= n4) return;
  float4 v = reinterpret_cast<const float4*>(in)[i];
  ushort4 o;
  o.x = f2bf(v.x); o.y = f2bf(v.y); o.z = f2bf(v.z); o.w = f2bf(v.w);
  reinterpret_cast<ushort4*>(out)[i] = o;
}

// ------------- transpose fp32 [K][N] -> bf16 [N][K] -------------
__global__ __launch_bounds__(256) void k_transpose(const float* __restrict__ W,
                                                   ushort* __restrict__ Wt,
                                                   int N, int K) {
  __shared__ float tile[32][33];
  int bx = blockIdx.x * 32;  // N dim
  int by = blockIdx.y * 32;  // K dim
  int tx = threadIdx.x, ty = threadIdx.y;  // 32 x 8
#pragma unroll
  for (int i = 0; i < 32; i += 8)
    tile[ty + i][tx] = W[(size_t)(by + ty + i) * N + bx + tx];
  __syncthreads();
#pragma unroll
  for (int i = 0; i < 32; i += 8)
    Wt[(size_t)(bx + ty + i) * K + by + tx] = f2bf(tile[tx][ty + i]);
}

// ------------- GEMM: C[M][N] fp32 = A[M][K] bf16 * Bt[N][K] bf16 -------------
// 128x128 tile, BK=32, 256 threads (4 waves, 2x2 of 64x64), mfma 16x16x32 bf16
__global__ __launch_bounds__(256) void k_gemm(const ushort* __restrict__ A,
                                              const ushort* __restrict__ Bt,
                                              float* __restrict__ C,
                                              int K, int N) {
  __shared__ ushort lsA[128][40];
  __shared__ ushort lsB[128][40];
  const int tid = threadIdx.x;
  const int bm = blockIdx.x, bn = blockIdx.y;
  const int w = tid >> 6, l = tid & 63;
  const int wm = (w >> 1) * 64, wn = (w & 1) * 64;
  const int lr = l & 15, lg = l >> 4;
  f32x4 acc[4][4] = {};
  const int sr = tid >> 2;          // 0..63
  const int sk = (tid & 3) * 8;     // 0,8,16,24
  const ushort* Ag = A + (size_t)bm * 128 * K + (size_t)sr * K + sk;
  const ushort* Bg = Bt + (size_t)bn * 128 * K + (size_t)sr * K + sk;
  uint4 a0 = *(const uint4*)(Ag);
  uint4 a1 = *(const uint4*)(Ag + (size_t)64 * K);
  uint4 b0 = *(const uint4*)(Bg);
  uint4 b1 = *(const uint4*)(Bg + (size_t)64 * K);
  for (int kt = 0; kt < K; kt += 32) {
    __syncthreads();
    *(uint4*)&lsA[sr][sk] = a0;
    *(uint4*)&lsA[sr + 64][sk] = a1;
    *(uint4*)&lsB[sr][sk] = b0;
    *(uint4*)&lsB[sr + 64][sk] = b1;
    __syncthreads();
    if (kt + 32 < K) {
      a0 = *(const uint4*)(Ag + kt + 32);
      a1 = *(const uint4*)(Ag + (size_t)64 * K + kt + 32);
      b0 = *(const uint4*)(Bg + kt + 32);
      b1 = *(const uint4*)(Bg + (size_t)64 * K + kt + 32);
    }
    short8 af[4], bfr[4];
#pragma unroll
    for (int i = 0; i < 4; ++i)
      af[i] = *(const short8*)&lsA[wm + i * 16 + lr][lg * 8];
#pragma unroll
    for (int j = 0; j < 4; ++j)
      bfr[j] = *(const short8*)&lsB[wn + j * 16 + lr][lg * 8];
#pragma unroll
    for (int i = 0; i < 4; ++i)
#pragma unroll
      for (int j = 0; j < 4; ++j)
        acc[i][j] = __builtin_amdgcn_mfma_f32_16x16x32_bf16(af[i], bfr[j], acc[i][j], 0, 0, 0);
  }
  float* Cb = C + (size_t)(bm * 128 + wm + lg * 4) * N + bn * 128 + wn + lr;
#pragma unroll
  for (int i = 0; i < 4; ++i)
#pragma unroll
    for (int j = 0; j < 4; ++j)
#pragma unroll
      for (int r = 0; r < 4; ++r)
        Cb[(size_t)(i * 16 + r) * N + j * 16] = acc[i][j][r];
}

// ------------- SRU recurrence -------------
// U: [B*L][2*512*KK] fp32; Xres (KK==3): [B*L][1024] bf16; H out: [B*L][1024] bf16
// One thread per (b, dir, h) channel; PF-deep register prefetch pipeline to get
// ~PF*14B*64 lanes in flight per wave (1 wave/CU -> need ~9-14 KB for HBM BW).
template <int KK, int PF>
__global__ __launch_bounds__(64) void sru_rec(const float* __restrict__ U,
                                              const ushort* __restrict__ Xres,
                                              const float* __restrict__ v,
                                              const float* __restrict__ bb,
                                              ushort* __restrict__ H) {
  int tid = blockIdx.x * 64 + threadIdx.x;
  int b = tid >> 10, rem = tid & 1023, dir = rem >> 9, h = rem & 511;
  float vf = v[dir * 512 + h], vr = v[1024 + dir * 512 + h];
  float bfv = bb[dir * 512 + h], brv = bb[1024 + dir * 512 + h];
  const int rs = 1024 * KK;
  const float* Ub = U + (size_t)b * 512 * rs + dir * 512 * KK + h * KK;
  const ushort* Xb = Xres + (size_t)b * 512 * 1024 + dir * 512 + h;
  ushort* Hb = H + (size_t)b * 512 * 1024 + dir * 512 + h;
  const int tstep = dir ? -1 : 1;
  const int t0 = dir ? 511 : 0;

  float p0[PF], p1[PF], p2[PF], p3[PF];
#pragma unroll
  for (int s = 0; s < PF; ++s) {
    int t = t0 + tstep * s;
    const float* up = Ub + (size_t)t * rs;
    p0[s] = up[0]; p1[s] = up[1]; p2[s] = up[2];
    p3[s] = (KK == 4) ? up[3] : bf2f(Xb[(size_t)t * 1024]);
  }
  float c = 0.f;
  for (int blk = 0; blk < 512; blk += PF) {
#pragma unroll
    for (int s = 0; s < PF; ++s) {
      const int step = blk + s;
      float u0 = p0[s], u1 = p1[s], u2 = p2[s], u3 = p3[s];
      if (step + PF < 512) {
        int tn = t0 + tstep * (step + PF);
        const float* up = Ub + (size_t)tn * rs;
        p0[s] = up[0]; p1[s] = up[1]; p2[s] = up[2];
        p3[s] = (KK == 4) ? up[3] : bf2f(Xb[(size_t)tn * 1024]);
      }
      float f = 1.f / (1.f + __expf(-(u1 + vf * c + bfv)));
      c = f * c + (1.f - f) * u0;
      float r = 1.f / (1.f + __expf(-(u2 + vr * c + brv)));
      float hh = r * c + (1.f - r) * u3;
      Hb[(size_t)(t0 + tstep * step) * 1024] = f2bf(hh);
    }
  }
}

// ------------- head: fc2s + log_softmax / tanh / softplus -------------
__global__ __launch_bounds__(256) void k_head(const float* __restrict__ Hcat,
                                              const float* __restrict__ b1l,
                                              const float* __restrict__ b1a,
                                              const float* __restrict__ w2l,
                                              const float* __restrict__ b2l,
                                              const float* __restrict__ w2m,
                                              const float* __restrict__ b2m,
                                              const float* __restrict__ w2k,
                                              const float* __restrict__ b2k,
                                              float* __restrict__ out) {
  __shared__ float hl[512], ha[512];
  __shared__ float part[25][8];
  __shared__ float vals[25];
  __shared__ float lse;
  const int row = blockIdx.x;
  const int tid = threadIdx.x;
  const float* Hr = Hcat + (size_t)row * 1024;
  for (int i = tid; i < 512; i += 256) {
    hl[i] = Hr[i] + b1l[i];
    ha[i] = Hr[512 + i] + b1a[i];
  }
  __syncthreads();
  const int o = tid >> 3, g = tid & 7;
  if (o < 25) {
    float s = 0.f;
    const int k0 = g * 64;
    if (o < 21) {
#pragma unroll 4
      for (int k = 0; k < 64; ++k) s += hl[k0 + k] * w2l[(size_t)(k0 + k) * 21 + o];
    } else if (o < 23) {
      for (int k = 0; k < 64; ++k) s += ha[k0 + k] * w2m[(k0 + k) * 2 + (o - 21)];
    } else {
      for (int k = 0; k < 64; ++k) s += ha[k0 + k] * w2k[(k0 + k) * 2 + (o - 23)];
    }
    part[o][g] = s;
  }
  __syncthreads();
  if (tid < 25) {
    float s = 0.f;
#pragma unroll
    for (int gg = 0; gg < 8; ++gg) s += part[tid][gg];
    s += (tid < 21) ? b2l[tid] : (tid < 23) ? b2m[tid - 21] : b2k[tid - 23];
    vals[tid] = s;
  }
  __syncthreads();
  if (tid == 0) {
    float m = vals[0];
    for (int j = 1; j < 21; ++j) m = fmaxf(m, vals[j]);
    float ss = 0.f;
    for (int j = 0; j < 21; ++j) ss += expf(vals[j] - m);
    lse = m + logf(ss);
  }
  __syncthreads();
  if (tid < 21) {
    out[(size_t)row * 21 + tid] = vals[tid] - lse;
  } else if (tid < 23) {
    out[172032 + row * 2 + (tid - 21)] = tanhf(vals[tid]) * 3.14159265358979323846f;
  } else if (tid < 25) {
    float x = vals[tid];
    float sp = (x > 20.f) ? x : log1pf(expf(x));
    out[188416 + row * 2 + (tid - 23)] = 5.f + sp;
  }
}

extern "C" void kernel_launch(void* const* d_in, const int* in_sizes, int n_in,
                              void* d_out, int out_size, void* d_ws, size_t ws_size,
                              hipStream_t stream) {
  (void)in_sizes; (void)n_in; (void)out_size; (void)ws_size;
  const float* input = (const float*)d_in[0];
  const float* sw[6]; const float* sv[6]; const float* sb[6];
  for (int l = 0; l < 6; ++l) {
    sw[l] = (const float*)d_in[2 + 3 * l];
    sv[l] = (const float*)d_in[3 + 3 * l];
    sb[l] = (const float*)d_in[4 + 3 * l];
  }
  const float* fc1lw = (const float*)d_in[20];
  const float* fc1lb = (const float*)d_in[21];
  const float* fc2lw = (const float*)d_in[22];
  const float* fc2lb = (const float*)d_in[23];
  const float* fc1aw = (const float*)d_in[24];
  const float* fc1ab = (const float*)d_in[25];
  const float* fc2mw = (const float*)d_in[26];
  const float* fc2mb = (const float*)d_in[27];
  const float* fc2kw = (const float*)d_in[28];
  const float* fc2kb = (const float*)d_in[29];

  char* ws = (char*)d_ws;
  float* U = (float*)ws;                                   // 128 MiB (also reused as Hcat)
  ushort* H0 = (ushort*)(ws + 134217728);                  // 16 MiB
  ushort* H1 = (ushort*)(ws + 150994944);                  // 16 MiB
  ushort* X0 = (ushort*)(ws + 167772160);                  // 8 MiB
  const size_t wbase = 176160768;
  ushort* Wtl[6];
  Wtl[0] = (ushort*)(ws + wbase);                          // 4 MiB
  for (int l = 1; l < 6; ++l)
    Wtl[l] = (ushort*)(ws + wbase + 4194304 + (size_t)(l - 1) * 6291456);  // 6 MiB each
  ushort* Wfc = (ushort*)(ws + wbase + 4194304 + 5ull * 6291456);          // 2 MiB
  float* Hcat = U;

  // 1. input -> bf16
  k_cvt<<<4096, 256, 0, stream>>>(input, X0, 8192 * 512 / 4);

  // 2. weight transposes -> bf16 [N][K]
  k_transpose<<<dim3(4096 / 32, 512 / 32), dim3(32, 8), 0, stream>>>(sw[0], Wtl[0], 4096, 512);
  for (int l = 1; l < 6; ++l)
    k_transpose<<<dim3(3072 / 32, 1024 / 32), dim3(32, 8), 0, stream>>>(sw[l], Wtl[l], 3072, 1024);
  k_transpose<<<dim3(512 / 32, 1024 / 32), dim3(32, 8), 0, stream>>>(fc1lw, Wfc, 512, 1024);
  k_transpose<<<dim3(512 / 32, 1024 / 32), dim3(32, 8), 0, stream>>>(fc1aw, Wfc + (size_t)512 * 1024, 512, 1024);

  // 3. SRU layers
  for (int l = 0; l < 6; ++l) {
    const ushort* Ain = (l == 0) ? X0 : ((l & 1) ? H0 : H1);
    ushort* Hout = (l & 1) ? H1 : H0;
    int K = (l == 0) ? 512 : 1024;
    int N = (l == 0) ? 4096 : 3072;
    k_gemm<<<dim3(64, N / 128), 256, 0, stream>>>(Ain, Wtl[l], U, K, N);
    if (l == 0)
      sru_rec<4, 16><<<256, 64, 0, stream>>>(U, X0 /*unused*/, sv[l], sb[l], Hout);
    else
      sru_rec<3, 16><<<256, 64, 0, stream>>>(U, Ain, sv[l], sb[l], Hout);
  }

  // 4. head fc1 (logits|angles fused): [8192,1024] = H5[8192,1024] x Wfc[1024,1024]
  k_gemm<<<dim3(64, 8), 256, 0, stream>>>(H1, Wfc, Hcat, 1024, 1024);

  // 5. head fc2 + activations
  k_head<<<8192, 256, 0, stream>>>(Hcat, fc1lb, fc1ab, fc2lw, fc2lb, fc2mw, fc2mb,
                                   fc2kw, fc2kb, (float*)d_out);
}

// Round 4
// 1100.665 us; speedup vs baseline: 1.8664x; 1.7253x over previous
//
#include <hip/hip_runtime.h>

typedef __attribute__((ext_vector_type(8))) short short8;
typedef __attribute__((ext_vector_type(4))) float f32x4;

__device__ __forceinline__ ushort f2bf(float x) {
  unsigned u = __builtin_bit_cast(unsigned, x);
  u = (u + 0x7fffu + ((u >> 16) & 1u)) >> 16;
  return (ushort)u;
}
__device__ __forceinline__ float bf2f(ushort x) {
  return __builtin_bit_cast(float, ((unsigned)x) << 16);
}

// global -> LDS direct DMA (size literal; only HW-verified 4 and 16 used)
#define AS1CP(p) ((const __attribute__((address_space(1))) unsigned int*)(p))
#define AS3CP(p) ((__attribute__((address_space(3))) unsigned int*)(p))
#define GLDS(g, l, SZ) __builtin_amdgcn_global_load_lds(AS1CP(g), AS3CP(l), SZ, 0, 0)

// ---------------- input fp32 -> bf16 ----------------
__global__ __launch_bounds__(256) void k_cvt(const float* __restrict__ in,
                                             ushort* __restrict__ out, int n4) {
  int i = blockIdx.x * 256 + threadIdx.x;
  if (i >= n4) return;
  float4 v = reinterpret_cast<const float4*>(in)[i];
  ushort4 o;
  o.x = f2bf(v.x); o.y = f2bf(v.y); o.z = f2bf(v.z); o.w = f2bf(v.w);
  reinterpret_cast<ushort4*>(out)[i] = o;
}

// ------------- transpose fp32 [K][N] -> bf16 [N][K] -------------
__global__ __launch_bounds__(256) void k_transpose(const float* __restrict__ W,
                                                   ushort* __restrict__ Wt,
                                                   int N, int K) {
  __shared__ float tile[32][33];
  int bx = blockIdx.x * 32;  // N dim
  int by = blockIdx.y * 32;  // K dim
  int tx = threadIdx.x, ty = threadIdx.y;  // 32 x 8
#pragma unroll
  for (int i = 0; i < 32; i += 8)
    tile[ty + i][tx] = W[(size_t)(by + ty + i) * N + bx + tx];
  __syncthreads();
#pragma unroll
  for (int i = 0; i < 32; i += 8)
    Wt[(size_t)(bx + ty + i) * K + by + tx] = f2bf(tile[tx][ty + i]);
}

// ------------- GEMM: C[M][N] fp32 = A[M][K] bf16 * Bt[N][K] bf16 -------------
__global__ __launch_bounds__(256) void k_gemm(const ushort* __restrict__ A,
                                              const ushort* __restrict__ Bt,
                                              float* __restrict__ C,
                                              int K, int N) {
  __shared__ ushort lsA[128][40];
  __shared__ ushort lsB[128][40];
  const int tid = threadIdx.x;
  const int bm = blockIdx.x, bn = blockIdx.y;
  const int w = tid >> 6, l = tid & 63;
  const int wm = (w >> 1) * 64, wn = (w & 1) * 64;
  const int lr = l & 15, lg = l >> 4;
  f32x4 acc[4][4] = {};
  const int sr = tid >> 2;          // 0..63
  const int sk = (tid & 3) * 8;     // 0,8,16,24
  const ushort* Ag = A + (size_t)bm * 128 * K + (size_t)sr * K + sk;
  const ushort* Bg = Bt + (size_t)bn * 128 * K + (size_t)sr * K + sk;
  uint4 a0 = *(const uint4*)(Ag);
  uint4 a1 = *(const uint4*)(Ag + (size_t)64 * K);
  uint4 b0 = *(const uint4*)(Bg);
  uint4 b1 = *(const uint4*)(Bg + (size_t)64 * K);
  for (int kt = 0; kt < K; kt += 32) {
    __syncthreads();
    *(uint4*)&lsA[sr][sk] = a0;
    *(uint4*)&lsA[sr + 64][sk] = a1;
    *(uint4*)&lsB[sr][sk] = b0;
    *(uint4*)&lsB[sr + 64][sk] = b1;
    __syncthreads();
    if (kt + 32 < K) {
      a0 = *(const uint4*)(Ag + kt + 32);
      a1 = *(const uint4*)(Ag + (size_t)64 * K + kt + 32);
      b0 = *(const uint4*)(Bg + kt + 32);
      b1 = *(const uint4*)(Bg + (size_t)64 * K + kt + 32);
    }
    short8 af[4], bfr[4];
#pragma unroll
    for (int i = 0; i < 4; ++i)
      af[i] = *(const short8*)&lsA[wm + i * 16 + lr][lg * 8];
#pragma unroll
    for (int j = 0; j < 4; ++j)
      bfr[j] = *(const short8*)&lsB[wn + j * 16 + lr][lg * 8];
#pragma unroll
    for (int i = 0; i < 4; ++i)
#pragma unroll
      for (int j = 0; j < 4; ++j)
        acc[i][j] = __builtin_amdgcn_mfma_f32_16x16x32_bf16(af[i], bfr[j], acc[i][j], 0, 0, 0);
  }
  float* Cb = C + (size_t)(bm * 128 + wm + lg * 4) * N + bn * 128 + wn + lr;
#pragma unroll
  for (int i = 0; i < 4; ++i)
#pragma unroll
    for (int j = 0; j < 4; ++j)
#pragma unroll
      for (int r = 0; r < 4; ++r)
        Cb[(size_t)(i * 16 + r) * N + j * 16] = acc[i][j][r];
}

// ------------- SRU recurrence v3: global_load_lds ring pipeline -------------
// Block = (b, dir, 64-channel chunk); one wave. LDS ring of 4 tiles of TS=16
// timesteps; tile i+3 issued while computing tile i; counted vmcnt waits that
// count ONLY loads issued after tile i's last load (loads retire in order on
// vmcnt; stores may not).
// U LDS layout: per step 64 lanes x 16B (KK3 over-reads 1 float; same cache
// lines from HBM). Per-tile loads: KK4 = 16; KK3 = 16 U + 8 X = 24.
template <int KK>
__device__ __forceinline__ void issue_tile(const float* Ub, const ushort* Xb,
                                           float* ldsu, ushort* ldsx, int i,
                                           int t0, int tstep, int lane, int c0,
                                           int rs) {
  const int base = i * 16;
#pragma unroll
  for (int t = 0; t < 16; ++t) {
    int tt = t0 + tstep * (base + t);
    GLDS(Ub + (size_t)tt * rs, ldsu + t * 256, 16);
  }
  if (KK == 3) {
#pragma unroll
    for (int tp = 0; tp < 8; ++tp) {
      int tt = t0 + tstep * (base + tp * 2 + (lane >> 5));
      GLDS(Xb + (size_t)tt * 1024 + c0 + ((lane & 31) << 1), ldsx + tp * 128, 4);
    }
  }
}

template <int KK>
__device__ __forceinline__ void tile_wait(int i) {
  if (KK == 3) {  // 24 loads/tile; newer loads: steady 72 (cap 63), 48, 24, 0
    if (i <= 28)
      asm volatile("s_waitcnt vmcnt(63)" ::: "memory");
    else if (i == 29)
      asm volatile("s_waitcnt vmcnt(48)" ::: "memory");
    else if (i == 30)
      asm volatile("s_waitcnt vmcnt(24)" ::: "memory");
    else
      asm volatile("s_waitcnt vmcnt(0)" ::: "memory");
  } else {        // 16 loads/tile; newer loads: steady 48, 32, 16, 0
    if (i <= 28)
      asm volatile("s_waitcnt vmcnt(48)" ::: "memory");
    else if (i == 29)
      asm volatile("s_waitcnt vmcnt(32)" ::: "memory");
    else if (i == 30)
      asm volatile("s_waitcnt vmcnt(16)" ::: "memory");
    else
      asm volatile("s_waitcnt vmcnt(0)" ::: "memory");
  }
}

template <int KK>
__device__ __forceinline__ void compute_tile(const float* tu, const ushort* tx,
                                             int i, int t0, int tstep, int lane,
                                             float vf, float vr, float bfv,
                                             float brv, float& c, ushort* Hb) {
#pragma unroll
  for (int s = 0; s < 16; ++s) {
    float4 p = *(const float4*)(tu + s * 256 + lane * 4);
    float u0 = p.x, u1 = p.y, u2 = p.z;
    float u3 = (KK == 4) ? p.w : bf2f(tx[s * 64 + lane]);
    float f = 1.f / (1.f + __expf(-(u1 + vf * c + bfv)));
    c = f * c + (1.f - f) * u0;
    float r = 1.f / (1.f + __expf(-(u2 + vr * c + brv)));
    float hh = r * c + (1.f - r) * u3;
    Hb[(size_t)(t0 + tstep * (i * 16 + s)) * 1024] = f2bf(hh);
  }
}

template <int KK>
__global__ __launch_bounds__(64) void sru_rec2(const float* __restrict__ U,
                                               const ushort* __restrict__ Xres,
                                               const float* __restrict__ v,
                                               const float* __restrict__ bb,
                                               ushort* __restrict__ H) {
  const int NT = 32;
  __shared__ __align__(16) float lsU[4][16 * 256];   // 64 KB
  __shared__ __align__(16) ushort lsX[4][16 * 64];   // 8 KB (KK3 only)
  const int lane = threadIdx.x;
  const int blk = blockIdx.x;                            // 0..255
  const int b = blk >> 4, rem = blk & 15, dir = rem >> 3, c0 = (rem & 7) << 6;
  const int h = c0 + lane;
  const float vf = v[dir * 512 + h], vr = v[1024 + dir * 512 + h];
  const float bfv = bb[dir * 512 + h], brv = bb[1024 + dir * 512 + h];
  const int rs = 1024 * KK;
  const int tstep = dir ? -1 : 1;
  const int t0 = dir ? 511 : 0;
  const float* Ub = U + (size_t)b * 512 * rs + dir * 512 * KK + (size_t)h * KK;
  const ushort* Xb = Xres + (size_t)b * 512 * 1024 + dir * 512;
  ushort* Hb = H + (size_t)b * 512 * 1024 + dir * 512 + h;

  issue_tile<KK>(Ub, Xb, &lsU[0][0], &lsX[0][0], 0, t0, tstep, lane, c0, rs);
  issue_tile<KK>(Ub, Xb, &lsU[1][0], &lsX[1][0], 1, t0, tstep, lane, c0, rs);
  issue_tile<KK>(Ub, Xb, &lsU[2][0], &lsX[2][0], 2, t0, tstep, lane, c0, rs);

  float c = 0.f;
#pragma unroll 1
  for (int ii = 0; ii < NT / 4; ++ii) {
#define TILE_J(J)                                                              \
    {                                                                          \
      const int i = ii * 4 + (J);                                              \
      if (i + 3 < NT)                                                          \
        issue_tile<KK>(Ub, Xb, &lsU[((J) + 3) & 3][0], &lsX[((J) + 3) & 3][0], \
                       i + 3, t0, tstep, lane, c0, rs);                        \
      tile_wait<KK>(i);                                                        \
      compute_tile<KK>(&lsU[(J) & 3][0], &lsX[(J) & 3][0], i, t0, tstep, lane, \
                       vf, vr, bfv, brv, c, Hb);                               \
    }
    TILE_J(0) TILE_J(1) TILE_J(2) TILE_J(3)
#undef TILE_J
  }
}

// ------------- head: fc2s + log_softmax / tanh / softplus -------------
__global__ __launch_bounds__(256) void k_head(const float* __restrict__ Hcat,
                                              const float* __restrict__ b1l,
                                              const float* __restrict__ b1a,
                                              const float* __restrict__ w2l,
                                              const float* __restrict__ b2l,
                                              const float* __restrict__ w2m,
                                              const float* __restrict__ b2m,
                                              const float* __restrict__ w2k,
                                              const float* __restrict__ b2k,
                                              float* __restrict__ out) {
  __shared__ float hl[512], ha[512];
  __shared__ float part[25][8];
  __shared__ float vals[25];
  __shared__ float lse;
  const int row = blockIdx.x;
  const int tid = threadIdx.x;
  const float* Hr = Hcat + (size_t)row * 1024;
  for (int i = tid; i < 512; i += 256) {
    hl[i] = Hr[i] + b1l[i];
    ha[i] = Hr[512 + i] + b1a[i];
  }
  __syncthreads();
  const int o = tid >> 3, g = tid & 7;
  if (o < 25) {
    float s = 0.f;
    const int k0 = g * 64;
    if (o < 21) {
#pragma unroll 4
      for (int k = 0; k < 64; ++k) s += hl[k0 + k] * w2l[(size_t)(k0 + k) * 21 + o];
    } else if (o < 23) {
      for (int k = 0; k < 64; ++k) s += ha[k0 + k] * w2m[(k0 + k) * 2 + (o - 21)];
    } else {
      for (int k = 0; k < 64; ++k) s += ha[k0 + k] * w2k[(k0 + k) * 2 + (o - 23)];
    }
    part[o][g] = s;
  }
  __syncthreads();
  if (tid < 25) {
    float s = 0.f;
#pragma unroll
    for (int gg = 0; gg < 8; ++gg) s += part[tid][gg];
    s += (tid < 21) ? b2l[tid] : (tid < 23) ? b2m[tid - 21] : b2k[tid - 23];
    vals[tid] = s;
  }
  __syncthreads();
  if (tid == 0) {
    float m = vals[0];
    for (int j = 1; j < 21; ++j) m = fmaxf(m, vals[j]);
    float ss = 0.f;
    for (int j = 0; j < 21; ++j) ss += expf(vals[j] - m);
    lse = m + logf(ss);
  }
  __syncthreads();
  if (tid < 21) {
    out[(size_t)row * 21 + tid] = vals[tid] - lse;
  } else if (tid < 23) {
    out[172032 + row * 2 + (tid - 21)] = tanhf(vals[tid]) * 3.14159265358979323846f;
  } else if (tid < 25) {
    float x = vals[tid];
    float sp = (x > 20.f) ? x : log1pf(expf(x));
    out[188416 + row * 2 + (tid - 23)] = 5.f + sp;
  }
}

extern "C" void kernel_launch(void* const* d_in, const int* in_sizes, int n_in,
                              void* d_out, int out_size, void* d_ws, size_t ws_size,
                              hipStream_t stream) {
  (void)in_sizes; (void)n_in; (void)out_size; (void)ws_size;
  const float* input = (const float*)d_in[0];
  const float* sw[6]; const float* sv[6]; const float* sb[6];
  for (int l = 0; l < 6; ++l) {
    sw[l] = (const float*)d_in[2 + 3 * l];
    sv[l] = (const float*)d_in[3 + 3 * l];
    sb[l] = (const float*)d_in[4 + 3 * l];
  }
  const float* fc1lw = (const float*)d_in[20];
  const float* fc1lb = (const float*)d_in[21];
  const float* fc2lw = (const float*)d_in[22];
  const float* fc2lb = (const float*)d_in[23];
  const float* fc1aw = (const float*)d_in[24];
  const float* fc1ab = (const float*)d_in[25];
  const float* fc2mw = (const float*)d_in[26];
  const float* fc2mb = (const float*)d_in[27];
  const float* fc2kw = (const float*)d_in[28];
  const float* fc2kb = (const float*)d_in[29];

  char* ws = (char*)d_ws;
  float* U = (float*)ws;                                   // 128 MiB (also reused as Hcat)
  ushort* H0 = (ushort*)(ws + 134217728);                  // 16 MiB
  ushort* H1 = (ushort*)(ws + 150994944);                  // 16 MiB
  ushort* X0 = (ushort*)(ws + 167772160);                  // 8 MiB
  const size_t wbase = 176160768;
  ushort* Wtl[6];
  Wtl[0] = (ushort*)(ws + wbase);                          // 4 MiB
  for (int l = 1; l < 6; ++l)
    Wtl[l] = (ushort*)(ws + wbase + 4194304 + (size_t)(l - 1) * 6291456);  // 6 MiB each
  ushort* Wfc = (ushort*)(ws + wbase + 4194304 + 5ull * 6291456);          // 2 MiB
  float* Hcat = U;

  // 1. input -> bf16
  k_cvt<<<4096, 256, 0, stream>>>(input, X0, 8192 * 512 / 4);

  // 2. weight transposes -> bf16 [N][K]
  k_transpose<<<dim3(4096 / 32, 512 / 32), dim3(32, 8), 0, stream>>>(sw[0], Wtl[0], 4096, 512);
  for (int l = 1; l < 6; ++l)
    k_transpose<<<dim3(3072 / 32, 1024 / 32), dim3(32, 8), 0, stream>>>(sw[l], Wtl[l], 3072, 1024);
  k_transpose<<<dim3(512 / 32, 1024 / 32), dim3(32, 8), 0, stream>>>(fc1lw, Wfc, 512, 1024);
  k_transpose<<<dim3(512 / 32, 1024 / 32), dim3(32, 8), 0, stream>>>(fc1aw, Wfc + (size_t)512 * 1024, 512, 1024);

  // 3. SRU layers
  for (int l = 0; l < 6; ++l) {
    const ushort* Ain = (l == 0) ? X0 : ((l & 1) ? H0 : H1);
    ushort* Hout = (l & 1) ? H1 : H0;
    int K = (l == 0) ? 512 : 1024;
    int N = (l == 0) ? 4096 : 3072;
    k_gemm<<<dim3(64, N / 128), 256, 0, stream>>>(Ain, Wtl[l], U, K, N);
    if (l == 0)
      sru_rec2<4><<<256, 64, 0, stream>>>(U, X0 /*unused*/, sv[l], sb[l], Hout);
    else
      sru_rec2<3><<<256, 64, 0, stream>>>(U, Ain, sv[l], sb[l], Hout);
  }

  // 4. head fc1 (logits|angles fused): [8192,1024] = H5[8192,1024] x Wfc[1024,1024]
  k_gemm<<<dim3(64, 8), 256, 0, stream>>>(H1, Wfc, Hcat, 1024, 1024);

  // 5. head fc2 + activations
  k_head<<<8192, 256, 0, stream>>>(Hcat, fc1lb, fc1ab, fc2lw, fc2lb, fc2mw, fc2mb,
                                   fc2kw, fc2kb, (float*)d_out);
}